// Round 1
// baseline (1349.101 us; speedup 1.0000x reference)
//
#include <hip/hip_runtime.h>

#define N_NODES 100000
#define N_EDGES 1600000

// ---------------- degree / normalization ----------------

__global__ void deg_kernel(const int* __restrict__ dst, float* __restrict__ deg, int E) {
    int e = blockIdx.x * blockDim.x + threadIdx.x;
    if (e < E) atomicAdd(&deg[dst[e]], 1.0f);
}

// in-place: deg -> dis = rsqrt(deg + 1)   (+1 = self loop)
__global__ void dis_kernel(float* __restrict__ deg, int n) {
    int i = blockIdx.x * blockDim.x + threadIdx.x;
    if (i < n) deg[i] = rsqrtf(deg[i] + 1.0f);
}

// ---------------- dense GEMM: y[n,DOUT] = x[n,DIN] @ W[DIN,DOUT] ----------------
// block = ROWS * DOUT threads; W and the block's x-rows staged in LDS.

template <int DIN, int DOUT, int ROWS>
__global__ void gemm_kernel(const float* __restrict__ x, const float* __restrict__ W,
                            float* __restrict__ y, int n) {
    __shared__ float Wl[DIN * DOUT];
    __shared__ float Xl[ROWS * DIN];

    for (int i = threadIdx.x; i < DIN * DOUT; i += blockDim.x) Wl[i] = W[i];

    const int row0 = blockIdx.x * ROWS;
    for (int i = threadIdx.x; i < ROWS * DIN; i += blockDim.x) {
        int r = row0 + i / DIN;
        Xl[i] = (r < n) ? x[(long)r * DIN + (i % DIN)] : 0.0f;
    }
    __syncthreads();

    const int local = threadIdx.x / DOUT;   // row within block
    const int col   = threadIdx.x % DOUT;
    const int row   = row0 + local;
    if (row >= n) return;

    float acc = 0.0f;
    const float* xr = &Xl[local * DIN];
#pragma unroll
    for (int k = 0; k < DIN; ++k) acc += xr[k] * Wl[k * DOUT + col];

    y[(long)row * DOUT + col] = acc;
}

// ---------------- edge scatter: out[dst] += y[src] * dis[src]*dis[dst] ----------------
// One DOUT-lane group per edge; lane = column -> coalesced atomics.

template <int DOUT>
__global__ void scatter_kernel(const int* __restrict__ src, const int* __restrict__ dst,
                               const float* __restrict__ dis, const float* __restrict__ y,
                               float* __restrict__ out, int E) {
    const int per_block = blockDim.x / DOUT;
    const int e = blockIdx.x * per_block + threadIdx.x / DOUT;
    const int c = threadIdx.x % DOUT;
    if (e >= E) return;
    const int s = src[e];
    const int d = dst[e];
    const float nm = dis[s] * dis[d];
    atomicAdd(&out[(long)d * DOUT + c], y[(long)s * DOUT + c] * nm);
}

// ---------------- epilogue: add self-loop term + bias, optional ReLU ----------------

template <int DOUT, bool RELU>
__global__ void epilogue_kernel(float* __restrict__ out, const float* __restrict__ y,
                                const float* __restrict__ dis, const float* __restrict__ b,
                                int n) {
    const int i = blockIdx.x * blockDim.x + threadIdx.x;
    const int node = i / DOUT;
    const int c = i % DOUT;
    if (node >= n) return;
    const float di = dis[node];
    float v = out[i] + y[i] * di * di + b[c];
    if (RELU) v = fmaxf(v, 0.0f);
    out[i] = v;
}

// ---------------- launch ----------------

extern "C" void kernel_launch(void* const* d_in, const int* in_sizes, int n_in,
                              void* d_out, int out_size, void* d_ws, size_t ws_size,
                              hipStream_t stream) {
    const float* features = (const float*)d_in[0];
    const int*   ei       = (const int*)d_in[1];
    const float* W0 = (const float*)d_in[2];
    const float* b0 = (const float*)d_in[3];
    const float* W1 = (const float*)d_in[4];
    const float* b1 = (const float*)d_in[5];
    const float* W2 = (const float*)d_in[6];
    const float* b2 = (const float*)d_in[7];

    const int* src = ei;             // edge_index[0]
    const int* dst = ei + N_EDGES;   // edge_index[1]

    const int n = N_NODES;
    const int E = N_EDGES;

    // workspace layout (floats)
    float* dis  = (float*)d_ws;                     // N_NODES
    float* bufA = dis + 131072;                     // N_NODES * 64
    float* bufB = bufA + (size_t)N_NODES * 64;      // N_NODES * 64
    float* outf = (float*)d_out;                    // N_NODES * 32

    // ---- degree / dis ----
    hipMemsetAsync(dis, 0, (size_t)n * sizeof(float), stream);
    deg_kernel<<<(E + 255) / 256, 256, 0, stream>>>(dst, dis, E);
    dis_kernel<<<(n + 255) / 256, 256, 0, stream>>>(dis, n);

    // ---- layer 0: 128 -> 64, ReLU ----
    gemm_kernel<128, 64, 4><<<(n + 3) / 4, 256, 0, stream>>>(features, W0, bufA, n);
    hipMemsetAsync(bufB, 0, (size_t)n * 64 * sizeof(float), stream);
    scatter_kernel<64><<<(E + 3) / 4, 256, 0, stream>>>(src, dst, dis, bufA, bufB, E);
    epilogue_kernel<64, true><<<(n * 64 + 255) / 256, 256, 0, stream>>>(bufB, bufA, dis, b0, n);

    // ---- layer 1: 64 -> 64, ReLU ----
    gemm_kernel<64, 64, 4><<<(n + 3) / 4, 256, 0, stream>>>(bufB, W1, bufA, n);
    hipMemsetAsync(bufB, 0, (size_t)n * 64 * sizeof(float), stream);
    scatter_kernel<64><<<(E + 3) / 4, 256, 0, stream>>>(src, dst, dis, bufA, bufB, E);
    epilogue_kernel<64, true><<<(n * 64 + 255) / 256, 256, 0, stream>>>(bufB, bufA, dis, b1, n);

    // ---- layer 2: 64 -> 32, no ReLU ----
    gemm_kernel<64, 32, 8><<<(n + 7) / 8, 256, 0, stream>>>(bufB, W2, bufA, n);
    hipMemsetAsync(outf, 0, (size_t)n * 32 * sizeof(float), stream);
    scatter_kernel<32><<<(E + 7) / 8, 256, 0, stream>>>(src, dst, dis, bufA, outf, E);
    epilogue_kernel<32, false><<<(n * 32 + 255) / 256, 256, 0, stream>>>(outf, bufA, dis, b2, n);
}

// Round 2
// 682.249 us; speedup vs baseline: 1.9774x; 1.9774x over previous
//
#include <hip/hip_runtime.h>

#define N_NODES 100000
#define N_EDGES 1600000

// ---------------- degree histogram (int) ----------------

__global__ void deg_kernel(const int* __restrict__ dst, int* __restrict__ deg, int E) {
    int e = blockIdx.x * blockDim.x + threadIdx.x;
    if (e < E) atomicAdd(&deg[dst[e]], 1);
}

// dis[i] = rsqrt(deg[i] + 1)   (+1 = self loop)
__global__ void dis_kernel(const int* __restrict__ deg, float* __restrict__ dis, int n) {
    int i = blockIdx.x * blockDim.x + threadIdx.x;
    if (i < n) dis[i] = rsqrtf((float)deg[i] + 1.0f);
}

// ---------------- exclusive scan of deg -> rowptr (3-kernel, 1024 elems/block) ----------------

__global__ void scan_block_kernel(const int* __restrict__ deg, int* __restrict__ excl,
                                  int* __restrict__ bsums, int n) {
    __shared__ int sh[256];
    const int base = blockIdx.x * 1024 + threadIdx.x * 4;
    int v0 = (base + 0 < n) ? deg[base + 0] : 0;
    int v1 = (base + 1 < n) ? deg[base + 1] : 0;
    int v2 = (base + 2 < n) ? deg[base + 2] : 0;
    int v3 = (base + 3 < n) ? deg[base + 3] : 0;
    int s = v0 + v1 + v2 + v3;
    sh[threadIdx.x] = s;
    __syncthreads();
    for (int off = 1; off < 256; off <<= 1) {
        int t = (threadIdx.x >= off) ? sh[threadIdx.x - off] : 0;
        __syncthreads();
        sh[threadIdx.x] += t;
        __syncthreads();
    }
    int run = sh[threadIdx.x] - s;  // exclusive prefix of this thread within block
    if (threadIdx.x == 255) bsums[blockIdx.x] = sh[255];
    if (base + 0 < n) excl[base + 0] = run;  run += v0;
    if (base + 1 < n) excl[base + 1] = run;  run += v1;
    if (base + 2 < n) excl[base + 2] = run;  run += v2;
    if (base + 3 < n) excl[base + 3] = run;
}

__global__ void scan_sums_kernel(int* __restrict__ bsums, int nb) {
    __shared__ int sh[128];
    int v = (threadIdx.x < nb) ? bsums[threadIdx.x] : 0;
    sh[threadIdx.x] = v;
    __syncthreads();
    for (int off = 1; off < 128; off <<= 1) {
        int t = (threadIdx.x >= off) ? sh[threadIdx.x - off] : 0;
        __syncthreads();
        sh[threadIdx.x] += t;
        __syncthreads();
    }
    if (threadIdx.x < nb) bsums[threadIdx.x] = sh[threadIdx.x] - v;  // exclusive
}

__global__ void add_offsets_kernel(int* __restrict__ rowptr, const int* __restrict__ bsums, int n) {
    int i = blockIdx.x * blockDim.x + threadIdx.x;
    if (i < n) rowptr[i] += bsums[i >> 10];
}

// ---------------- fill CSR: edges sorted by dst, payload = (src, norm) ----------------

__global__ void fill_kernel(const int* __restrict__ src, const int* __restrict__ dst,
                            const int* __restrict__ rowptr, int* __restrict__ fill,
                            const float* __restrict__ dis, int2* __restrict__ edges, int E) {
    int e = blockIdx.x * blockDim.x + threadIdx.x;
    if (e >= E) return;
    int s = src[e];
    int d = dst[e];
    int pos = rowptr[d] + atomicAdd(&fill[d], 1);
    float nm = dis[s] * dis[d];
    edges[pos] = make_int2(s, __float_as_int(nm));
}

// ---------------- dense GEMM: y[n,DOUT] = x[n,DIN] @ W[DIN,DOUT] ----------------

template <int DIN, int DOUT, int ROWS>
__global__ void gemm_kernel(const float* __restrict__ x, const float* __restrict__ W,
                            float* __restrict__ y, int n) {
    __shared__ float Wl[DIN * DOUT];
    __shared__ float Xl[ROWS * DIN];

    for (int i = threadIdx.x; i < DIN * DOUT; i += blockDim.x) Wl[i] = W[i];

    const int row0 = blockIdx.x * ROWS;
    for (int i = threadIdx.x; i < ROWS * DIN; i += blockDim.x) {
        int r = row0 + i / DIN;
        Xl[i] = (r < n) ? x[(long)r * DIN + (i % DIN)] : 0.0f;
    }
    __syncthreads();

    const int local = threadIdx.x / DOUT;
    const int col   = threadIdx.x % DOUT;
    const int row   = row0 + local;
    if (row >= n) return;

    float acc = 0.0f;
    const float* xr = &Xl[local * DIN];
#pragma unroll
    for (int k = 0; k < DIN; ++k) acc += xr[k] * Wl[k * DOUT + col];

    y[(long)row * DOUT + col] = acc;
}

// ---------------- per-node gather + fused self-loop/bias/ReLU ----------------
// One DOUT-lane group per node; lane = output column.

template <int DOUT, bool RELU>
__global__ void gather_kernel(const int* __restrict__ rowptr, const int* __restrict__ deg,
                              const int2* __restrict__ edges, const float* __restrict__ y,
                              const float* __restrict__ dis, const float* __restrict__ b,
                              float* __restrict__ out, int n) {
    const int node = blockIdx.x * (blockDim.x / DOUT) + threadIdx.x / DOUT;
    const int c = threadIdx.x % DOUT;
    if (node >= n) return;

    const float di = dis[node];
    float acc = y[(long)node * DOUT + c] * di * di + b[c];

    const int beg = rowptr[node];
    const int end = beg + deg[node];
    int k = beg;
    for (; k + 4 <= end; k += 4) {
        int2 e0 = edges[k], e1 = edges[k + 1], e2 = edges[k + 2], e3 = edges[k + 3];
        float v0 = y[(long)e0.x * DOUT + c];
        float v1 = y[(long)e1.x * DOUT + c];
        float v2 = y[(long)e2.x * DOUT + c];
        float v3 = y[(long)e3.x * DOUT + c];
        acc += v0 * __int_as_float(e0.y);
        acc += v1 * __int_as_float(e1.y);
        acc += v2 * __int_as_float(e2.y);
        acc += v3 * __int_as_float(e3.y);
    }
    for (; k < end; ++k) {
        int2 e = edges[k];
        acc += y[(long)e.x * DOUT + c] * __int_as_float(e.y);
    }

    if (RELU) acc = fmaxf(acc, 0.0f);
    out[(long)node * DOUT + c] = acc;
}

// ---------------- launch ----------------

extern "C" void kernel_launch(void* const* d_in, const int* in_sizes, int n_in,
                              void* d_out, int out_size, void* d_ws, size_t ws_size,
                              hipStream_t stream) {
    const float* features = (const float*)d_in[0];
    const int*   ei       = (const int*)d_in[1];
    const float* W0 = (const float*)d_in[2];
    const float* b0 = (const float*)d_in[3];
    const float* W1 = (const float*)d_in[4];
    const float* b1 = (const float*)d_in[5];
    const float* W2 = (const float*)d_in[6];
    const float* b2 = (const float*)d_in[7];

    const int* src = ei;             // edge_index[0]
    const int* dst = ei + N_EDGES;   // edge_index[1]

    const int n = N_NODES;
    const int E = N_EDGES;
    const int nb = (n + 1023) / 1024;  // 98 scan blocks

    // workspace layout (int-sized slots, 128K-aligned chunks)
    int*   deg    = (int*)d_ws;                          // [0, 131072)
    float* dis    = (float*)d_ws + 131072;               // [131072, 262144)
    int*   rowptr = (int*)d_ws + 262144;                 // [262144, 393216)
    int*   fill   = (int*)d_ws + 393216;                 // [393216, 524288)
    int*   bsums  = (int*)d_ws + 524288;                 // [524288, 525312)
    int2*  edges  = (int2*)((int*)d_ws + 525312);        // E int2 = 3.2M ints
    float* bufA   = (float*)d_ws + 525312 + 2 * N_EDGES;        // N*64
    float* bufB   = bufA + (size_t)N_NODES * 64;                // N*64
    float* outf   = (float*)d_out;                              // N*32

    // ---- CSR build (once per call, reused by all 3 layers) ----
    hipMemsetAsync(deg, 0, (size_t)n * sizeof(int), stream);
    hipMemsetAsync(fill, 0, (size_t)n * sizeof(int), stream);
    deg_kernel<<<(E + 255) / 256, 256, 0, stream>>>(dst, deg, E);
    dis_kernel<<<(n + 255) / 256, 256, 0, stream>>>(deg, dis, n);
    scan_block_kernel<<<nb, 256, 0, stream>>>(deg, rowptr, bsums, n);
    scan_sums_kernel<<<1, 128, 0, stream>>>(bsums, nb);
    add_offsets_kernel<<<(n + 255) / 256, 256, 0, stream>>>(rowptr, bsums, n);
    fill_kernel<<<(E + 255) / 256, 256, 0, stream>>>(src, dst, rowptr, fill, dis, edges, E);

    // ---- layer 0: 128 -> 64, ReLU ----
    gemm_kernel<128, 64, 4><<<(n + 3) / 4, 256, 0, stream>>>(features, W0, bufA, n);
    gather_kernel<64, true><<<(n + 3) / 4, 256, 0, stream>>>(rowptr, deg, edges, bufA, dis, b0, bufB, n);

    // ---- layer 1: 64 -> 64, ReLU ----
    gemm_kernel<64, 64, 4><<<(n + 3) / 4, 256, 0, stream>>>(bufB, W1, bufA, n);
    gather_kernel<64, true><<<(n + 3) / 4, 256, 0, stream>>>(rowptr, deg, edges, bufA, dis, b1, bufB, n);

    // ---- layer 2: 64 -> 32, no ReLU ----
    gemm_kernel<64, 32, 8><<<(n + 7) / 8, 256, 0, stream>>>(bufB, W2, bufA, n);
    gather_kernel<32, false><<<(n + 7) / 8, 256, 0, stream>>>(rowptr, deg, edges, bufA, dis, b2, outf, n);
}

// Round 3
// 517.607 us; speedup vs baseline: 2.6064x; 1.3181x over previous
//
#include <hip/hip_runtime.h>

#define N_NODES 100000
#define N_EDGES 1600000

// ---------------- degree histogram (int) ----------------

__global__ void deg_kernel(const int* __restrict__ dst, int* __restrict__ deg, int E) {
    int e = blockIdx.x * blockDim.x + threadIdx.x;
    if (e < E) atomicAdd(&deg[dst[e]], 1);
}

// dis[i] = rsqrt(deg[i] + 1)   (+1 = self loop)
__global__ void dis_kernel(const int* __restrict__ deg, float* __restrict__ dis, int n) {
    int i = blockIdx.x * blockDim.x + threadIdx.x;
    if (i < n) dis[i] = rsqrtf((float)deg[i] + 1.0f);
}

// ---------------- exclusive scan of deg -> rowptr ----------------

__global__ void scan_block_kernel(const int* __restrict__ deg, int* __restrict__ excl,
                                  int* __restrict__ bsums, int n) {
    __shared__ int sh[256];
    const int base = blockIdx.x * 1024 + threadIdx.x * 4;
    int v0 = (base + 0 < n) ? deg[base + 0] : 0;
    int v1 = (base + 1 < n) ? deg[base + 1] : 0;
    int v2 = (base + 2 < n) ? deg[base + 2] : 0;
    int v3 = (base + 3 < n) ? deg[base + 3] : 0;
    int s = v0 + v1 + v2 + v3;
    sh[threadIdx.x] = s;
    __syncthreads();
    for (int off = 1; off < 256; off <<= 1) {
        int t = (threadIdx.x >= off) ? sh[threadIdx.x - off] : 0;
        __syncthreads();
        sh[threadIdx.x] += t;
        __syncthreads();
    }
    int run = sh[threadIdx.x] - s;
    if (threadIdx.x == 255) bsums[blockIdx.x] = sh[255];
    if (base + 0 < n) excl[base + 0] = run;  run += v0;
    if (base + 1 < n) excl[base + 1] = run;  run += v1;
    if (base + 2 < n) excl[base + 2] = run;  run += v2;
    if (base + 3 < n) excl[base + 3] = run;
}

__global__ void scan_sums_kernel(int* __restrict__ bsums, int nb) {
    __shared__ int sh[128];
    int v = (threadIdx.x < nb) ? bsums[threadIdx.x] : 0;
    sh[threadIdx.x] = v;
    __syncthreads();
    for (int off = 1; off < 128; off <<= 1) {
        int t = (threadIdx.x >= off) ? sh[threadIdx.x - off] : 0;
        __syncthreads();
        sh[threadIdx.x] += t;
        __syncthreads();
    }
    if (threadIdx.x < nb) bsums[threadIdx.x] = sh[threadIdx.x] - v;
}

__global__ void add_offsets_kernel(int* __restrict__ rowptr, const int* __restrict__ bsums, int n) {
    int i = blockIdx.x * blockDim.x + threadIdx.x;
    if (i < n) rowptr[i] += bsums[i >> 10];
}

// ---------------- fill CSR: edges sorted by dst, payload = (src, norm) ----------------

__global__ void fill_kernel(const int* __restrict__ src, const int* __restrict__ dst,
                            const int* __restrict__ rowptr, int* __restrict__ fill,
                            const float* __restrict__ dis, int2* __restrict__ edges, int E) {
    int e = blockIdx.x * blockDim.x + threadIdx.x;
    if (e >= E) return;
    int s = src[e];
    int d = dst[e];
    int pos = rowptr[d] + atomicAdd(&fill[d], 1);
    float nm = dis[s] * dis[d];
    edges[pos] = make_int2(s, __float_as_int(nm));
}

// ---------------- W transpose: Wt[c*DIN + k] = W[k*DOUT + c] ----------------

__global__ void transpose_w_kernel(const float* __restrict__ W, float* __restrict__ Wt,
                                   int din, int dout) {
    int i = blockIdx.x * blockDim.x + threadIdx.x;
    if (i < din * dout) {
        int k = i / dout, c = i % dout;
        Wt[c * din + k] = W[i];
    }
}

// ---------------- dense GEMM: y[n,DOUT] = x[n,DIN] @ W[DIN,DOUT] ----------------
// Wt is pre-transposed [DOUT][DIN]. Each thread: 1 row x 4 strided cols.
// Inner loop: 1 float4 x-read (broadcast) + 4 float4 W-reads per 16 FMAs.

template <int DIN, int DOUT>
__global__ void __launch_bounds__(256) gemm_kernel(const float* __restrict__ x,
                                                   const float* __restrict__ Wt,
                                                   float* __restrict__ y, int n) {
    constexpr int TPR  = DOUT / 4;    // threads per row
    constexpr int ROWS = 256 / TPR;   // rows per block
    constexpr int WS   = DIN + 4;     // padded LDS stride (keeps 16B align, breaks bank stride)

    __shared__ float Wl[DOUT * WS];
    __shared__ float Xl[ROWS * WS];

    // stage Wt (float4 read, float4 write, conflict-free)
    for (int i = 4 * threadIdx.x; i < DIN * DOUT; i += 1024) {
        float4 v = *(const float4*)&Wt[i];
        int c = i / DIN, k = i % DIN;
        *(float4*)&Wl[c * WS + k] = v;
    }

    // stage x rows
    const int row0 = blockIdx.x * ROWS;
    for (int i = 4 * threadIdx.x; i < ROWS * DIN; i += 1024) {
        int r = i / DIN, k = i % DIN;
        float4 v = make_float4(0.f, 0.f, 0.f, 0.f);
        if (row0 + r < n) v = *(const float4*)&x[(long)(row0 + r) * DIN + k];
        *(float4*)&Xl[r * WS + k] = v;
    }
    __syncthreads();

    const int lrow = threadIdx.x / TPR;
    const int c0   = threadIdx.x % TPR;
    const int row  = row0 + lrow;
    if (row >= n) return;

    float acc0 = 0.f, acc1 = 0.f, acc2 = 0.f, acc3 = 0.f;
    const float* xr = &Xl[lrow * WS];
    const float* w0 = &Wl[(c0 + 0 * TPR) * WS];
    const float* w1 = &Wl[(c0 + 1 * TPR) * WS];
    const float* w2 = &Wl[(c0 + 2 * TPR) * WS];
    const float* w3 = &Wl[(c0 + 3 * TPR) * WS];

#pragma unroll 4
    for (int k = 0; k < DIN; k += 4) {
        float4 xv = *(const float4*)&xr[k];
        float4 a = *(const float4*)&w0[k];
        float4 b = *(const float4*)&w1[k];
        float4 c = *(const float4*)&w2[k];
        float4 d = *(const float4*)&w3[k];
        acc0 += xv.x * a.x + xv.y * a.y + xv.z * a.z + xv.w * a.w;
        acc1 += xv.x * b.x + xv.y * b.y + xv.z * b.z + xv.w * b.w;
        acc2 += xv.x * c.x + xv.y * c.y + xv.z * c.z + xv.w * c.w;
        acc3 += xv.x * d.x + xv.y * d.y + xv.z * d.z + xv.w * d.w;
    }

    float* yr = &y[(long)row * DOUT];
    yr[c0 + 0 * TPR] = acc0;
    yr[c0 + 1 * TPR] = acc1;
    yr[c0 + 2 * TPR] = acc2;
    yr[c0 + 3 * TPR] = acc3;
}

// ---------------- per-node gather + fused self-loop/bias/ReLU ----------------

template <int DOUT, bool RELU>
__global__ void gather_kernel(const int* __restrict__ rowptr, const int* __restrict__ deg,
                              const int2* __restrict__ edges, const float* __restrict__ y,
                              const float* __restrict__ dis, const float* __restrict__ b,
                              float* __restrict__ out, int n) {
    const int node = blockIdx.x * (blockDim.x / DOUT) + threadIdx.x / DOUT;
    const int c = threadIdx.x % DOUT;
    if (node >= n) return;

    const float di = dis[node];
    float acc = y[(long)node * DOUT + c] * di * di + b[c];

    const int beg = rowptr[node];
    const int end = beg + deg[node];
    int k = beg;
    for (; k + 4 <= end; k += 4) {
        int2 e0 = edges[k], e1 = edges[k + 1], e2 = edges[k + 2], e3 = edges[k + 3];
        float v0 = y[(long)e0.x * DOUT + c];
        float v1 = y[(long)e1.x * DOUT + c];
        float v2 = y[(long)e2.x * DOUT + c];
        float v3 = y[(long)e3.x * DOUT + c];
        acc += v0 * __int_as_float(e0.y);
        acc += v1 * __int_as_float(e1.y);
        acc += v2 * __int_as_float(e2.y);
        acc += v3 * __int_as_float(e3.y);
    }
    for (; k < end; ++k) {
        int2 e = edges[k];
        acc += y[(long)e.x * DOUT + c] * __int_as_float(e.y);
    }

    if (RELU) acc = fmaxf(acc, 0.0f);
    out[(long)node * DOUT + c] = acc;
}

// ---------------- launch ----------------

extern "C" void kernel_launch(void* const* d_in, const int* in_sizes, int n_in,
                              void* d_out, int out_size, void* d_ws, size_t ws_size,
                              hipStream_t stream) {
    const float* features = (const float*)d_in[0];
    const int*   ei       = (const int*)d_in[1];
    const float* W0 = (const float*)d_in[2];
    const float* b0 = (const float*)d_in[3];
    const float* W1 = (const float*)d_in[4];
    const float* b1 = (const float*)d_in[5];
    const float* W2 = (const float*)d_in[6];
    const float* b2 = (const float*)d_in[7];

    const int* src = ei;             // edge_index[0]
    const int* dst = ei + N_EDGES;   // edge_index[1]

    const int n = N_NODES;
    const int E = N_EDGES;
    const int nb = (n + 1023) / 1024;

    // workspace layout (float/int slots)
    int*   deg    = (int*)d_ws;                          // 131072
    float* dis    = (float*)d_ws + 131072;
    int*   rowptr = (int*)d_ws + 262144;
    int*   fill   = (int*)d_ws + 393216;
    int*   bsums  = (int*)d_ws + 524288;                 // 1024
    int2*  edges  = (int2*)((int*)d_ws + 525312);        // E int2
    float* bufA   = (float*)d_ws + 525312 + 2 * N_EDGES; // N*64
    float* bufB   = bufA + (size_t)N_NODES * 64;         // N*64
    float* wt0    = bufB + (size_t)N_NODES * 64;         // 128*64
    float* wt1    = wt0 + 128 * 64;                      // 64*64
    float* wt2    = wt1 + 64 * 64;                       // 64*32
    float* outf   = (float*)d_out;                       // N*32

    // ---- CSR build + weight transposes (once per call) ----
    hipMemsetAsync(deg, 0, (size_t)n * sizeof(int), stream);
    hipMemsetAsync(fill, 0, (size_t)n * sizeof(int), stream);
    deg_kernel<<<(E + 255) / 256, 256, 0, stream>>>(dst, deg, E);
    dis_kernel<<<(n + 255) / 256, 256, 0, stream>>>(deg, dis, n);
    scan_block_kernel<<<nb, 256, 0, stream>>>(deg, rowptr, bsums, n);
    scan_sums_kernel<<<1, 128, 0, stream>>>(bsums, nb);
    add_offsets_kernel<<<(n + 255) / 256, 256, 0, stream>>>(rowptr, bsums, n);
    fill_kernel<<<(E + 255) / 256, 256, 0, stream>>>(src, dst, rowptr, fill, dis, edges, E);
    transpose_w_kernel<<<(128 * 64 + 255) / 256, 256, 0, stream>>>(W0, wt0, 128, 64);
    transpose_w_kernel<<<(64 * 64 + 255) / 256, 256, 0, stream>>>(W1, wt1, 64, 64);
    transpose_w_kernel<<<(64 * 32 + 255) / 256, 256, 0, stream>>>(W2, wt2, 64, 32);

    // ---- layer 0: 128 -> 64, ReLU ----
    gemm_kernel<128, 64><<<(n + 15) / 16, 256, 0, stream>>>(features, wt0, bufA, n);
    gather_kernel<64, true><<<(n + 3) / 4, 256, 0, stream>>>(rowptr, deg, edges, bufA, dis, b0, bufB, n);

    // ---- layer 1: 64 -> 64, ReLU ----
    gemm_kernel<64, 64><<<(n + 15) / 16, 256, 0, stream>>>(bufB, wt1, bufA, n);
    gather_kernel<64, true><<<(n + 3) / 4, 256, 0, stream>>>(rowptr, deg, edges, bufA, dis, b1, bufB, n);

    // ---- layer 2: 64 -> 32, no ReLU ----
    gemm_kernel<64, 32><<<(n + 31) / 32, 256, 0, stream>>>(bufB, wt2, bufA, n);
    gather_kernel<32, false><<<(n + 7) / 8, 256, 0, stream>>>(rowptr, deg, edges, bufA, dis, b2, outf, n);
}